// Round 6
// baseline (3795.410 us; speedup 1.0000x reference)
//
#include <hip/hip_runtime.h>
#include <hip/hip_bf16.h>

// Problem constants (N=64, D=64, H=64, W=64, K=512)
#define VQ_D   64
#define VQ_K   512
#define VQ_HW  4096
#define VQ_M   262144
#define VQ_LOSS_OFF 16777216
#define VQ_IDX_OFF  16777217
#define VQ_MARGIN   6.5e-5f
#define VQ_BIAS     0.25f

typedef __bf16 bf16x8v __attribute__((ext_vector_type(8)));
typedef float  f32x16  __attribute__((ext_vector_type(16)));

union BF8 { unsigned short u[8]; uint4 q4; bf16x8v v; };

// fp32 -> bf16 round-to-nearest-even
__device__ __forceinline__ unsigned short f2bf(float f) {
    unsigned u = __builtin_bit_cast(unsigned, f);
    u += 0x7FFFu + ((u >> 16) & 1u);
    return (unsigned short)(u >> 16);
}
__device__ __forceinline__ float bf2f(unsigned short b) {
    return __builtin_bit_cast(float, ((unsigned)b) << 16);
}

// ---------------------------------------------------------------------------
// Prep: esq[k] (numpy pairwise, bitwise-exact) + split-bf16 A-fragments.
// kfrag layout: [tile t(16)][frag f(9)][lane(64)] uint4.
//   f = q*2   : hi(-2*e[q*16+k]),  f = q*2+1 : lo remainder
//   f = 8     : bias row  (k=0 -> bf16_hi(0.25+esq), k=1 -> bf16_lo)
// A-frag convention (32x32x16): lane l holds A[m=l&31][k=(l>>5)*8+j].
// => acc = 0.25 + esq - 2*dot  (positive => uint-comparable), err ~3e-6.
// ---------------------------------------------------------------------------
__global__ void vq_prep(const float* __restrict__ emb, float* __restrict__ esq,
                        uint4* __restrict__ kfrag,
                        double* __restrict__ loss_acc, int* __restrict__ cnt) {
#pragma clang fp contract(off)
    int k = blockIdx.x * 256 + threadIdx.x;
    if (k == 0) { *loss_acc = 0.0; *cnt = 0; }
    if (k < VQ_K) {
        const float* e = emb + k * VQ_D;
        float p[VQ_D];
#pragma unroll
        for (int d = 0; d < VQ_D; ++d) p[d] = e[d] * e[d];
        float r[8];
#pragma unroll
        for (int j = 0; j < 8; ++j) r[j] = p[j];
#pragma unroll
        for (int i = 8; i < VQ_D; i += 8)
#pragma unroll
            for (int j = 0; j < 8; ++j) r[j] += p[i + j];
        float es = ((r[0] + r[1]) + (r[2] + r[3])) + ((r[4] + r[5]) + (r[6] + r[7]));
        esq[k] = es;

        float sc = VQ_BIAS + es;
        unsigned short bhi = f2bf(sc);
        unsigned short blo = f2bf(sc - bf2f(bhi));

        int t = k >> 5, c = k & 31;
#pragma unroll
        for (int q = 0; q < 4; ++q)
#pragma unroll
            for (int h = 0; h < 2; ++h) {
                BF8 th, tl;
#pragma unroll
                for (int j = 0; j < 8; ++j) {
                    float v = -2.0f * e[q * 16 + h * 8 + j];
                    unsigned short hi = f2bf(v);
                    th.u[j] = hi;
                    tl.u[j] = f2bf(v - bf2f(hi));
                }
                kfrag[(t * 9 + q * 2 + 0) * 64 + h * 32 + c] = th.q4;
                kfrag[(t * 9 + q * 2 + 1) * 64 + h * 32 + c] = tl.q4;
            }
        BF8 tb;
#pragma unroll
        for (int j = 0; j < 8; ++j) tb.u[j] = 0;
        tb.u[0] = bhi; tb.u[1] = blo;
        kfrag[(t * 9 + 8) * 64 + c] = tb.q4;          // half 0 (k=0,1 live)
        BF8 tz;
#pragma unroll
        for (int j = 0; j < 8; ++j) tz.u[j] = 0;
        kfrag[(t * 9 + 8) * 64 + 32 + c] = tz.q4;     // half 1 zeros
    }
}

// ---------------------------------------------------------------------------
// Screen + fused output. Block = 512 thr (8 waves) = 256 points.
// Per 32-code tile: 13 MFMAs (split-bf16) -> 16 scores/lane; packed-key
// top-2; xor-32 merge; flag gap<=margin; unflagged write z_q + loss here.
// ---------------------------------------------------------------------------
__global__ __launch_bounds__(512) void vq_screen(
        const float* __restrict__ z_e,
        const uint4* __restrict__ kfrag,
        const float* __restrict__ emb,
        float* __restrict__ out,
        float* __restrict__ out_idx,
        int* __restrict__ cnt,
        int* __restrict__ flag_list,
        double* __restrict__ loss_acc)
{
    __shared__ uint4 smem[2304];                      // 36 KB: 4 tiles x 9 frags
    const int tid = threadIdx.x;
    const int w   = tid >> 6;
    const int l   = tid & 63;
    const int c   = l & 31;
    const int h   = l >> 5;

    const int m0 = (blockIdx.x * 8 + w) * 32;         // wave's 32 points
    const int n  = m0 >> 12;
    const int hw = (m0 & 4095) + c;
    const float* zb = z_e + (size_t)n * (VQ_D * VQ_HW) + hw;

    // z as hi/lo bf16 B-frags: B[k=(l>>5)*8+j][col=l&31], d = q*16 + h*8 + j
    bf16x8v bzh[4], bzl[4];
#pragma unroll
    for (int q = 0; q < 4; ++q) {
        BF8 th, tl;
#pragma unroll
        for (int j = 0; j < 8; ++j) {
            float v = zb[(q * 16 + h * 8 + j) * VQ_HW];
            unsigned short hi = f2bf(v);
            th.u[j] = hi;
            tl.u[j] = f2bf(v - bf2f(hi));
        }
        bzh[q] = th.v; bzl[q] = tl.v;
    }
    BF8 tob;
#pragma unroll
    for (int j = 0; j < 8; ++j) tob.u[j] = 0;
    if (h == 0) { tob.u[0] = 0x3F80; tob.u[1] = 0x3F80; }  // B = (1,1,0,..)
    const bf16x8v bones = tob.v;

    int coder[16];
#pragma unroll
    for (int r = 0; r < 16; ++r) coder[r] = (r & 3) + 8 * (r >> 2) + 4 * h;

    unsigned m1 = 0xFFFFFFFFu, m2 = 0xFFFFFFFFu;
    const unsigned SMASK = 0xFFFFFE00u;

    for (int ph = 0; ph < 4; ++ph) {                  // 4 phases x 4 tiles
        __syncthreads();
#pragma unroll
        for (int i = 0; i < 5; ++i) {
            int idx = i * 512 + tid;
            if (idx < 2304) smem[idx] = kfrag[ph * 2304 + idx];
        }
        __syncthreads();

        for (int t4 = 0; t4 < 4; ++t4) {
            const int base = t4 * 9 * 64;
            f32x16 acc;
#pragma unroll
            for (int r = 0; r < 16; ++r) acc[r] = 0.f;
#pragma unroll
            for (int q = 0; q < 4; ++q) {
                bf16x8v ah = __builtin_bit_cast(bf16x8v, smem[base + (q * 2 + 0) * 64 + l]);
                bf16x8v al = __builtin_bit_cast(bf16x8v, smem[base + (q * 2 + 1) * 64 + l]);
                acc = __builtin_amdgcn_mfma_f32_32x32x16_bf16(ah, bzh[q], acc, 0, 0, 0);
                acc = __builtin_amdgcn_mfma_f32_32x32x16_bf16(ah, bzl[q], acc, 0, 0, 0);
                acc = __builtin_amdgcn_mfma_f32_32x32x16_bf16(al, bzh[q], acc, 0, 0, 0);
            }
            bf16x8v ab = __builtin_bit_cast(bf16x8v, smem[base + 8 * 64 + l]);
            acc = __builtin_amdgcn_mfma_f32_32x32x16_bf16(ab, bones, acc, 0, 0, 0);

#pragma unroll
            for (int r = 0; r < 16; ++r) {
                unsigned key = (__builtin_bit_cast(unsigned, acc[r]) & SMASK)
                               | (unsigned)coder[r];
                unsigned mx = m1 > key ? m1 : key;
                m2 = m2 < mx ? m2 : mx;
                m1 = m1 < key ? m1 : key;
                coder[r] += 32;
            }
        }
    }

    // merge complementary code halves (lane ^ 32)
    unsigned om1 = (unsigned)__shfl_xor((int)m1, 32, 64);
    unsigned om2 = (unsigned)__shfl_xor((int)m2, 32, 64);
    unsigned mx  = m1 > om1 ? m1 : om1;
    m1 = m1 < om1 ? m1 : om1;
    m2 = m2 < om2 ? m2 : om2;
    m2 = m2 < mx ? m2 : mx;

    const int   win = (int)(m1 & 511u);
    const float s1  = __builtin_bit_cast(float, m1 & SMASK);
    const float s2  = __builtin_bit_cast(float, m2 & SMASK);
    const bool  flagged = (s2 - s1) <= VQ_MARGIN;

    if (h == 0) out_idx[m0 + c] = (float)win;

    unsigned long long bal = __ballot(flagged);
    unsigned mask32 = (unsigned)(bal & 0xFFFFFFFFull);
    int cw = __popc(mask32);
    int basepos = 0;
    if (l == 0 && cw) basepos = atomicAdd(cnt, cw);
    basepos = __shfl(basepos, 0, 64);
    if (h == 0 && flagged)
        flag_list[basepos + __popc(mask32 & ((1u << c) - 1u))] = m0 + c;

    // fused z_q + loss for unflagged (z reconstructed from hi+lo, err 2^-17)
    float lsum = 0.f;
    if (!flagged) {
        const float* er = emb + (win << 6);
        float* op = out + (size_t)n * (VQ_D * VQ_HW) + hw;
#pragma unroll
        for (int q = 0; q < 4; ++q) {
            BF8 th, tl;
            th.v = bzh[q]; tl.v = bzl[q];
            float4 ea = *(const float4*)(er + q * 16 + h * 8);
            float4 e2 = *(const float4*)(er + q * 16 + h * 8 + 4);
            float ev[8] = {ea.x, ea.y, ea.z, ea.w, e2.x, e2.y, e2.z, e2.w};
#pragma unroll
            for (int j = 0; j < 8; ++j) {
                op[(q * 16 + h * 8 + j) * VQ_HW] = ev[j];
                float zv = bf2f(th.u[j]) + bf2f(tl.u[j]);
                float df = zv - ev[j];
                lsum = fmaf(df, df, lsum);
            }
        }
    }
    for (int off = 32; off > 0; off >>= 1)
        lsum += __shfl_down(lsum, off, 64);
    if (l == 0) atomicAdd(loss_acc, (double)lsum);
}

// ---------------------------------------------------------------------------
// Rescore: BLOCK per flagged point (grid-stride). 256 thr x 2 codes each,
// e-rows from global (L2-hot), z exact-fp32 in LDS, bitwise-numpy dist,
// u64 (dist_bits<<9)|code min-reduce = exact first-occurrence argmin.
// ---------------------------------------------------------------------------
__global__ __launch_bounds__(256) void vq_rescore(
        const float* __restrict__ z_e,
        const float* __restrict__ emb,
        const float* __restrict__ esq,
        float* __restrict__ out,
        float* __restrict__ out_idx,
        const int* __restrict__ cnt,
        const int* __restrict__ flag_list,
        double* __restrict__ loss_acc)
{
#pragma clang fp contract(off)
    __shared__ float zs[VQ_D];
    __shared__ unsigned long long wmin[4];
    __shared__ int winner;
    const int tid = threadIdx.x;
    const int total = *cnt;

    for (int it = blockIdx.x; it < total; it += gridDim.x) {
        __syncthreads();                               // zs/winner reuse guard
        const int m  = flag_list[it];
        const int n  = m >> 12;
        const int hw = m & 4095;
        if (tid < VQ_D)
            zs[tid] = z_e[(size_t)n * (VQ_D * VQ_HW) + tid * VQ_HW + hw];
        __syncthreads();

        // zsq: numpy pairwise (mul rounded, then add)
        float r[8];
#pragma unroll
        for (int j = 0; j < 8; ++j) r[j] = zs[j] * zs[j];
#pragma unroll
        for (int i = 8; i < VQ_D; i += 8)
#pragma unroll
            for (int j = 0; j < 8; ++j) {
                float t = zs[i + j] * zs[i + j];
                r[j] += t;
            }
        const float zsq = ((r[0] + r[1]) + (r[2] + r[3])) + ((r[4] + r[5]) + (r[6] + r[7]));

        const int k0 = tid * 2, k1 = tid * 2 + 1;
        const float* e0 = emb + k0 * VQ_D;
        const float* e1 = e0 + VQ_D;
        float a0 = 0.f, a1 = 0.f;
#pragma unroll
        for (int d = 0; d < VQ_D; ++d) {
            float zv = zs[d];
            a0 = __builtin_fmaf(zv, e0[d], a0);
            a1 = __builtin_fmaf(zv, e1[d], a1);
        }
        float d0 = (zsq + esq[k0]) - 2.0f * a0;
        float d1 = (zsq + esq[k1]) - 2.0f * a1;
        unsigned long long key0 = (((unsigned long long)__builtin_bit_cast(unsigned, d0)) << 9) | (unsigned)k0;
        unsigned long long key1 = (((unsigned long long)__builtin_bit_cast(unsigned, d1)) << 9) | (unsigned)k1;
        unsigned long long key = key0 < key1 ? key0 : key1;

#pragma unroll
        for (int off = 32; off > 0; off >>= 1) {
            unsigned long long o = __shfl_down(key, off, 64);
            key = o < key ? o : key;
        }
        if ((tid & 63) == 0) wmin[tid >> 6] = key;
        __syncthreads();
        if (tid == 0) {
            unsigned long long b = wmin[0];
            b = wmin[1] < b ? wmin[1] : b;
            b = wmin[2] < b ? wmin[2] : b;
            b = wmin[3] < b ? wmin[3] : b;
            int bw = (int)(b & 511ull);
            winner = bw;
            out_idx[m] = (float)bw;
        }
        __syncthreads();

        float lsum = 0.f;
        if (tid < VQ_D) {
            float q = emb[(winner << 6) + tid];
            out[(size_t)n * (VQ_D * VQ_HW) + tid * VQ_HW + hw] = q;
            float df = zs[tid] - q;
            lsum = df * df;
        }
        if (tid < 64) {
#pragma unroll
            for (int off = 32; off > 0; off >>= 1)
                lsum += __shfl_down(lsum, off, 64);
            if (tid == 0) atomicAdd(loss_acc, (double)lsum);
        }
    }
}

__global__ void vq_fin(const double* __restrict__ loss_acc, float* __restrict__ out) {
    if (threadIdx.x == 0)
        out[VQ_LOSS_OFF] = (float)(*loss_acc / 16777216.0);
}

extern "C" void kernel_launch(void* const* d_in, const int* in_sizes, int n_in,
                              void* d_out, int out_size, void* d_ws, size_t ws_size,
                              hipStream_t stream) {
    const float* z_e = (const float*)d_in[0];
    const float* emb = (const float*)d_in[1];
    float* out = (float*)d_out;
    float* out_idx = out + VQ_IDX_OFF;

    // ws layout:
    //   0      : double loss_acc                 (8 B)
    //   8      : int cnt                         (4 B + pad)
    //   16     : float esq[512]                  (2048 B)   -> 2064
    //   2064   : uint4 kfrag[9216]               (147456 B) -> 149520
    //   149520 : int flag_list[262144]           (1 MB)
    char* ws = (char*)d_ws;
    double* loss_acc  = (double*)ws;
    int*    cnt       = (int*)(ws + 8);
    float*  esq       = (float*)(ws + 16);
    uint4*  kfrag     = (uint4*)(ws + 2064);
    int*    flag_list = (int*)(ws + 149520);

    vq_prep<<<2, 256, 0, stream>>>(emb, esq, kfrag, loss_acc, cnt);
    vq_screen<<<VQ_M / 256, 512, 0, stream>>>(z_e, kfrag, emb, out, out_idx,
                                              cnt, flag_list, loss_acc);
    vq_rescore<<<4096, 256, 0, stream>>>(z_e, emb, esq, out, out_idx,
                                         cnt, flag_list, loss_acc);
    vq_fin<<<1, 64, 0, stream>>>(loss_acc, out);
}